// Round 3
// baseline (726.338 us; speedup 1.0000x reference)
//
#include <hip/hip_runtime.h>

#define N_NODES 100000
#define N_EDGES 1600000
#define F_IN    512
#define HIDDEN  16
#define N_CLS   40

#define BSHIFT  7
#define BSIZE   128                                // nodes per bucket
#define NB      ((N_NODES + BSIZE - 1) / BSIZE)    // 782 buckets
#define NWGBIN  256
#define CHUNK   (N_EDGES / NWGBIN)                 // 6250 (exact)

static_assert(N_EDGES % NWGBIN == 0, "chunking must be exact");

// ---------------- zero bucket counters ----------------
__global__ void k_zero(int* __restrict__ p, int n) {
    int i = blockIdx.x * blockDim.x + threadIdx.x;
    if (i < n) p[i] = 0;
}

// ---------------- pass A: per-bucket edge counts ----------------
__global__ __launch_bounds__(256) void k_binc(const int* __restrict__ ei,
                                              int* __restrict__ bucketCnt) {
    __shared__ int h[NB];
    int t = threadIdx.x;
    for (int b = t; b < NB; b += 256) h[b] = 0;
    __syncthreads();
    int start = blockIdx.x * CHUNK, end = start + CHUNK;
    for (int e = start + t; e < end; e += 256)
        atomicAdd(&h[ei[N_EDGES + e] >> BSHIFT], 1);
    __syncthreads();
    for (int b = t; b < NB; b += 256)
        if (h[b]) atomicAdd(&bucketCnt[b], h[b]);
}

// ---------------- exclusive scan of 782 bucket counts ----------------
__global__ __launch_bounds__(1024) void k_bscan(const int* __restrict__ bucketCnt,
                                                int* __restrict__ off,
                                                int* __restrict__ cur) {
    __shared__ int s[1024];
    int t = threadIdx.x;
    int v = (t < NB) ? bucketCnt[t] : 0;
    s[t] = v; __syncthreads();
    for (int o = 1; o < 1024; o <<= 1) {
        int add = (t >= o) ? s[t - o] : 0;
        __syncthreads();
        s[t] += add;
        __syncthreads();
    }
    if (t < NB) { int ex = s[t] - v; off[t] = ex; cur[t] = ex; }
    if (t == 0) off[NB] = N_EDGES;
}

// ---------------- pass B: place packed edges (r | lc<<17) ----------------
__global__ __launch_bounds__(256) void k_bfill(const int* __restrict__ ei,
                                               int* __restrict__ cur,
                                               int* __restrict__ binned) {
    __shared__ int lc[NB];
    int t = threadIdx.x;
    int start = blockIdx.x * CHUNK, end = start + CHUNK;
    for (int b = t; b < NB; b += 256) lc[b] = 0;
    __syncthreads();
    for (int e = start + t; e < end; e += 256)
        atomicAdd(&lc[ei[N_EDGES + e] >> BSHIFT], 1);
    __syncthreads();
    // reserve contiguous per-WG runs; lc becomes the local cursor (= global pos)
    for (int b = t; b < NB; b += 256) {
        int c = lc[b];
        lc[b] = c ? atomicAdd(&cur[b], c) : 0;
    }
    __syncthreads();
    for (int e = start + t; e < end; e += 256) {
        int r = ei[e], c = ei[N_EDGES + e];
        int b = c >> BSHIFT;
        int pos = atomicAdd(&lc[b], 1);
        binned[pos] = r | ((c & (BSIZE - 1)) << 17);
    }
}

// ---------------- per-node degree -> dis (from binned list, no atomics) ----
__global__ __launch_bounds__(256) void k_deg(const int* __restrict__ off,
                                             const int* __restrict__ binned,
                                             float* __restrict__ dis) {
    __shared__ int h[BSIZE];
    int t = threadIdx.x, b = blockIdx.x;
    if (t < BSIZE) h[t] = 0;
    __syncthreads();
    int s = off[b], e = off[b + 1];
    for (int i = s + t; i < e; i += 256)
        atomicAdd(&h[binned[i] >> 17], 1);
    __syncthreads();
    if (t < BSIZE) {
        int node = b * BSIZE + t;
        if (node < N_NODES) dis[node] = rsqrtf(1.0f + (float)h[t]);
    }
}

// ---------------- layer-1 GEMM: h1s = (x @ W1) * dis ----------------
// 4 lanes per row (128 cols each), 4 rows per thread (stride 64), 256 rows/WG.
__global__ __launch_bounds__(256) void k_gemm1(
        const float* __restrict__ x, const float* __restrict__ W1,
        const float* __restrict__ dis, float* __restrict__ h1s) {
    __shared__ float sW[F_IN * 20];   // stride 20: 16B-aligned float4 rows, banks spread
    for (int idx = threadIdx.x; idx < F_IN * HIDDEN; idx += 256) {
        int k = idx >> 4, j = idx & 15;
        sW[k * 20 + j] = W1[idx];
    }
    __syncthreads();

    int t = threadIdx.x;
    int q = t & 3;
    int rbase = blockIdx.x * 256 + (t >> 2);

    float acc[4][16];
#pragma unroll
    for (int rr = 0; rr < 4; ++rr)
#pragma unroll
        for (int j = 0; j < 16; ++j) acc[rr][j] = 0.0f;

    bool rok[4];
    const float* xr[4];
#pragma unroll
    for (int rr = 0; rr < 4; ++rr) {
        int row = rbase + rr * 64;
        rok[rr] = row < N_NODES;
        xr[rr] = x + (size_t)row * F_IN;
    }

#pragma unroll 2
    for (int i = 0; i < 32; ++i) {
        int k0 = i * 16 + q * 4;
        float4 xv[4];
#pragma unroll
        for (int rr = 0; rr < 4; ++rr)
            xv[rr] = rok[rr] ? *(const float4*)(xr[rr] + k0) : float4{0, 0, 0, 0};
#pragma unroll
        for (int kk = 0; kk < 4; ++kk) {
            const float* wr = &sW[(k0 + kk) * 20];
            float4 w0 = *(const float4*)(wr);
            float4 w1 = *(const float4*)(wr + 4);
            float4 w2 = *(const float4*)(wr + 8);
            float4 w3 = *(const float4*)(wr + 12);
#pragma unroll
            for (int rr = 0; rr < 4; ++rr) {
                float xs = (&xv[rr].x)[kk];
                acc[rr][0]  = fmaf(xs, w0.x, acc[rr][0]);
                acc[rr][1]  = fmaf(xs, w0.y, acc[rr][1]);
                acc[rr][2]  = fmaf(xs, w0.z, acc[rr][2]);
                acc[rr][3]  = fmaf(xs, w0.w, acc[rr][3]);
                acc[rr][4]  = fmaf(xs, w1.x, acc[rr][4]);
                acc[rr][5]  = fmaf(xs, w1.y, acc[rr][5]);
                acc[rr][6]  = fmaf(xs, w1.z, acc[rr][6]);
                acc[rr][7]  = fmaf(xs, w1.w, acc[rr][7]);
                acc[rr][8]  = fmaf(xs, w2.x, acc[rr][8]);
                acc[rr][9]  = fmaf(xs, w2.y, acc[rr][9]);
                acc[rr][10] = fmaf(xs, w2.z, acc[rr][10]);
                acc[rr][11] = fmaf(xs, w2.w, acc[rr][11]);
                acc[rr][12] = fmaf(xs, w3.x, acc[rr][12]);
                acc[rr][13] = fmaf(xs, w3.y, acc[rr][13]);
                acc[rr][14] = fmaf(xs, w3.z, acc[rr][14]);
                acc[rr][15] = fmaf(xs, w3.w, acc[rr][15]);
            }
        }
    }

    // reduce-scatter over the 4 lanes: lane q ends holding j in [4q, 4q+4)
#pragma unroll
    for (int rr = 0; rr < 4; ++rr) {
        float t16[16];
#pragma unroll
        for (int j = 0; j < 16; ++j)
            t16[j] = acc[rr][j] + __shfl_xor(acc[rr][j], 2);
        float k8[8];
#pragma unroll
        for (int j = 0; j < 8; ++j)
            k8[j] = (q & 2) ? t16[8 + j] : t16[j];
        float t8[8];
#pragma unroll
        for (int j = 0; j < 8; ++j)
            t8[j] = k8[j] + __shfl_xor(k8[j], 1);
#pragma unroll
        for (int j = 0; j < 4; ++j)
            acc[rr][j] = (q & 1) ? t8[4 + j] : t8[j];
    }

#pragma unroll
    for (int rr = 0; rr < 4; ++rr) {
        int row = rbase + rr * 64;
        if (rok[rr]) {
            float d = dis[row];
            float4 hv = { acc[rr][0] * d, acc[rr][1] * d, acc[rr][2] * d, acc[rr][3] * d };
            *(float4*)(h1s + (size_t)row * HIDDEN + q * 4) = hv;
        }
    }
}

// ---------------- agg layer 1: g = relu(dis*(self+Σ h1s[r]) + b1) * dis ----
__global__ __launch_bounds__(256) void k_agg1(
        const int* __restrict__ off, const int* __restrict__ binned,
        const float* __restrict__ dis, const float* __restrict__ b1,
        const float* __restrict__ h1s, float* __restrict__ g) {
    __shared__ float agg[BSIZE * 17];     // stride 17 breaks bank conflicts
    int t = threadIdx.x, b = blockIdx.x;
    for (int i = t; i < BSIZE * 17; i += 256) agg[i] = 0.0f;
    __syncthreads();

    int s = off[b], e = off[b + 1];
    int q = t & 3;
    for (int base = s; base < e; base += 128) {
        int e1 = base + (t >> 2);
        int e2 = e1 + 64;
        bool ok1 = e1 < e, ok2 = e2 < e;
        int p1 = ok1 ? binned[e1] : 0;
        int p2 = ok2 ? binned[e2] : 0;
        float4 v1 = {0,0,0,0}, v2 = {0,0,0,0};
        int a1 = 0, a2 = 0;
        if (ok1) {
            int r = p1 & 0x1FFFF, lcn = p1 >> 17;
            v1 = *(const float4*)(h1s + (size_t)r * HIDDEN + q * 4);
            a1 = lcn * 17 + q * 4;
        }
        if (ok2) {
            int r = p2 & 0x1FFFF, lcn = p2 >> 17;
            v2 = *(const float4*)(h1s + (size_t)r * HIDDEN + q * 4);
            a2 = lcn * 17 + q * 4;
        }
        if (ok1) {
            atomicAdd(&agg[a1 + 0], v1.x); atomicAdd(&agg[a1 + 1], v1.y);
            atomicAdd(&agg[a1 + 2], v1.z); atomicAdd(&agg[a1 + 3], v1.w);
        }
        if (ok2) {
            atomicAdd(&agg[a2 + 0], v2.x); atomicAdd(&agg[a2 + 1], v2.y);
            atomicAdd(&agg[a2 + 2], v2.z); atomicAdd(&agg[a2 + 3], v2.w);
        }
    }
    __syncthreads();

    int ln = t >> 1, half = t & 1;        // 2 threads per node, 8 feats each
    int node = b * BSIZE + ln;
    if (node < N_NODES) {
        float d = dis[node];
        int j0 = half * 8;
        const float* hp = h1s + (size_t)node * HIDDEN + j0;
        float4 s0 = *(const float4*)(hp);
        float4 s1 = *(const float4*)(hp + 4);
        const float* ap = &agg[ln * 17 + j0];
        float o[8];
#pragma unroll
        for (int k = 0; k < 4; ++k) {
            float a0 = ap[k] + (&s0.x)[k];
            o[k] = fmaxf(fmaf(a0, d, b1[j0 + k]), 0.0f) * d;
            float a1v = ap[4 + k] + (&s1.x)[k];
            o[4 + k] = fmaxf(fmaf(a1v, d, b1[j0 + 4 + k]), 0.0f) * d;
        }
        float* gp = g + (size_t)node * HIDDEN + j0;
        *(float4*)(gp)     = { o[0], o[1], o[2], o[3] };
        *(float4*)(gp + 4) = { o[4], o[5], o[6], o[7] };
    }
}

// ---------------- agg layer 2: out = b2 + (dis*(self+Σ g[r])) @ W2 ----------
__global__ __launch_bounds__(256) void k_agg2(
        const int* __restrict__ off, const int* __restrict__ binned,
        const float* __restrict__ dis, const float* __restrict__ W2,
        const float* __restrict__ b2, const float* __restrict__ g,
        float* __restrict__ out) {
    __shared__ float agg[BSIZE * 17];
    __shared__ float sW[HIDDEN * N_CLS];
    __shared__ float sb2[N_CLS];
    int t = threadIdx.x, b = blockIdx.x;
    for (int i = t; i < BSIZE * 17; i += 256) agg[i] = 0.0f;
    for (int i = t; i < HIDDEN * N_CLS; i += 256) sW[i] = W2[i];
    if (t < N_CLS) sb2[t] = b2[t];
    __syncthreads();

    int s = off[b], e = off[b + 1];
    int q = t & 3;
    for (int base = s; base < e; base += 128) {
        int e1 = base + (t >> 2);
        int e2 = e1 + 64;
        bool ok1 = e1 < e, ok2 = e2 < e;
        int p1 = ok1 ? binned[e1] : 0;
        int p2 = ok2 ? binned[e2] : 0;
        float4 v1 = {0,0,0,0}, v2 = {0,0,0,0};
        int a1 = 0, a2 = 0;
        if (ok1) {
            int r = p1 & 0x1FFFF, lcn = p1 >> 17;
            v1 = *(const float4*)(g + (size_t)r * HIDDEN + q * 4);
            a1 = lcn * 17 + q * 4;
        }
        if (ok2) {
            int r = p2 & 0x1FFFF, lcn = p2 >> 17;
            v2 = *(const float4*)(g + (size_t)r * HIDDEN + q * 4);
            a2 = lcn * 17 + q * 4;
        }
        if (ok1) {
            atomicAdd(&agg[a1 + 0], v1.x); atomicAdd(&agg[a1 + 1], v1.y);
            atomicAdd(&agg[a1 + 2], v1.z); atomicAdd(&agg[a1 + 3], v1.w);
        }
        if (ok2) {
            atomicAdd(&agg[a2 + 0], v2.x); atomicAdd(&agg[a2 + 1], v2.y);
            atomicAdd(&agg[a2 + 2], v2.z); atomicAdd(&agg[a2 + 3], v2.w);
        }
    }
    __syncthreads();

    int ln = t >> 1, half = t & 1;        // 2 threads per node, 20 out-cols each
    int node = b * BSIZE + ln;
    if (node < N_NODES) {
        float d = dis[node];
        const float* gs = g + (size_t)node * HIDDEN;
        float a[HIDDEN];
#pragma unroll
        for (int j4 = 0; j4 < 4; ++j4) {
            float4 sv = *(const float4*)(gs + j4 * 4);
            a[j4*4+0] = d * (agg[ln * 17 + j4*4+0] + sv.x);
            a[j4*4+1] = d * (agg[ln * 17 + j4*4+1] + sv.y);
            a[j4*4+2] = d * (agg[ln * 17 + j4*4+2] + sv.z);
            a[j4*4+3] = d * (agg[ln * 17 + j4*4+3] + sv.w);
        }
        int c0 = half * 20;
        float o[20];
#pragma unroll
        for (int k = 0; k < 20; ++k) o[k] = sb2[c0 + k];
#pragma unroll
        for (int j = 0; j < HIDDEN; ++j) {
            float aj = a[j];
            const float* wr = &sW[j * N_CLS + c0];
#pragma unroll
            for (int k = 0; k < 20; ++k) o[k] = fmaf(aj, wr[k], o[k]);
        }
        float* op = out + (size_t)node * N_CLS + c0;
#pragma unroll
        for (int k4 = 0; k4 < 5; ++k4)
            *(float4*)(op + k4 * 4) = { o[k4*4+0], o[k4*4+1], o[k4*4+2], o[k4*4+3] };
    }
}

extern "C" void kernel_launch(void* const* d_in, const int* in_sizes, int n_in,
                              void* d_out, int out_size, void* d_ws, size_t ws_size,
                              hipStream_t stream) {
    const float* x  = (const float*)d_in[0];
    const int*   ei = (const int*)d_in[1];
    const float* W1 = (const float*)d_in[2];
    const float* b1 = (const float*)d_in[3];
    const float* W2 = (const float*)d_in[4];
    const float* b2 = (const float*)d_in[5];
    float* out = (float*)d_out;

    // ws: bucketCnt[784] | off[784] | cur[784] | dis[100000] | binned[1.6M] |
    //     h1s[1.6M] | g[1.6M]   ≈ 19.7 MB
    char* w = (char*)d_ws;
    int*   bucketCnt = (int*)w;    w += 784 * 4;
    int*   off       = (int*)w;    w += 784 * 4;
    int*   cur       = (int*)w;    w += 784 * 4;
    float* dis       = (float*)w;  w += (size_t)N_NODES * 4;
    int*   binned    = (int*)w;    w += (size_t)N_EDGES * 4;
    float* h1s       = (float*)w;  w += (size_t)N_NODES * HIDDEN * 4;
    float* g         = (float*)w;

    const int gGemm = (N_NODES + 255) / 256;   // 391

    k_zero <<<(NB + 255) / 256, 256, 0, stream>>>(bucketCnt, NB);
    k_binc <<<NWGBIN, 256, 0, stream>>>(ei, bucketCnt);
    k_bscan<<<1, 1024, 0, stream>>>(bucketCnt, off, cur);
    k_bfill<<<NWGBIN, 256, 0, stream>>>(ei, cur, binned);
    k_deg  <<<NB, 256, 0, stream>>>(off, binned, dis);
    k_gemm1<<<gGemm, 256, 0, stream>>>(x, W1, dis, h1s);
    k_agg1 <<<NB, 256, 0, stream>>>(off, binned, dis, b1, h1s, g);
    k_agg2 <<<NB, 256, 0, stream>>>(off, binned, dis, W2, b2, g, out);
}

// Round 4
// 451.225 us; speedup vs baseline: 1.6097x; 1.6097x over previous
//
#include <hip/hip_runtime.h>

#define N_NODES 100000
#define N_EDGES 1600000
#define F_IN    512
#define HIDDEN  16
#define N_CLS   40

#define BSHIFT  7
#define BSIZE   128                                // nodes per bucket
#define NB      ((N_NODES + BSIZE - 1) / BSIZE)    // 782 buckets
#define NWGBIN  256
#define CHUNK   (N_EDGES / NWGBIN)                 // 6250 (exact)

static_assert(N_EDGES % NWGBIN == 0, "chunking must be exact");

// ---------------- zero bucket counters ----------------
__global__ void k_zero(int* __restrict__ p, int n) {
    int i = blockIdx.x * blockDim.x + threadIdx.x;
    if (i < n) p[i] = 0;
}

// ---------------- pass A: per-bucket edge counts ----------------
__global__ __launch_bounds__(256) void k_binc(const int* __restrict__ ei,
                                              int* __restrict__ bucketCnt) {
    __shared__ int h[NB];
    int t = threadIdx.x;
    for (int b = t; b < NB; b += 256) h[b] = 0;
    __syncthreads();
    int start = blockIdx.x * CHUNK, end = start + CHUNK;
    for (int e = start + t; e < end; e += 256)
        atomicAdd(&h[ei[N_EDGES + e] >> BSHIFT], 1);
    __syncthreads();
    for (int b = t; b < NB; b += 256)
        if (h[b]) atomicAdd(&bucketCnt[b], h[b]);
}

// ---------------- exclusive scan of 782 bucket counts ----------------
__global__ __launch_bounds__(1024) void k_bscan(const int* __restrict__ bucketCnt,
                                                int* __restrict__ boff,
                                                int* __restrict__ cur) {
    __shared__ int s[1024];
    int t = threadIdx.x;
    int v = (t < NB) ? bucketCnt[t] : 0;
    s[t] = v; __syncthreads();
    for (int o = 1; o < 1024; o <<= 1) {
        int add = (t >= o) ? s[t - o] : 0;
        __syncthreads();
        s[t] += add;
        __syncthreads();
    }
    if (t < NB) { int ex = s[t] - v; boff[t] = ex; cur[t] = ex; }
    if (t == 0) boff[NB] = N_EDGES;
}

// ---------------- pass B: place packed edges (r | lc<<17) ----------------
__global__ __launch_bounds__(256) void k_bfill(const int* __restrict__ ei,
                                               int* __restrict__ cur,
                                               int* __restrict__ binned) {
    __shared__ int lc[NB];
    int t = threadIdx.x;
    int start = blockIdx.x * CHUNK, end = start + CHUNK;
    for (int b = t; b < NB; b += 256) lc[b] = 0;
    __syncthreads();
    for (int e = start + t; e < end; e += 256)
        atomicAdd(&lc[ei[N_EDGES + e] >> BSHIFT], 1);
    __syncthreads();
    for (int b = t; b < NB; b += 256) {
        int c = lc[b];
        lc[b] = c ? atomicAdd(&cur[b], c) : 0;
    }
    __syncthreads();
    for (int e = start + t; e < end; e += 256) {
        int r = ei[e], c = ei[N_EDGES + e];
        int b = c >> BSHIFT;
        int pos = atomicAdd(&lc[b], 1);
        binned[pos] = r | ((c & (BSIZE - 1)) << 17);
    }
}

// ------ per-bucket counting sort: binned -> node-sorted csr + offsets/cnt/dis ----
__global__ __launch_bounds__(256) void k_csr(const int* __restrict__ boff,
                                             const int* __restrict__ binned,
                                             int* __restrict__ csr,
                                             int* __restrict__ offsets,
                                             int* __restrict__ cnt,
                                             float* __restrict__ dis) {
    __shared__ int h[BSIZE];      // per-local-node histogram
    __shared__ int sc[BSIZE];     // scan
    __shared__ int curL[BSIZE];   // local cursors (absolute csr positions)
    int t = threadIdx.x, b = blockIdx.x;
    if (t < BSIZE) h[t] = 0;
    __syncthreads();
    int s = boff[b], e = boff[b + 1];
    for (int i = s + t; i < e; i += 256)
        atomicAdd(&h[binned[i] >> 17], 1);
    __syncthreads();
    int v = (t < BSIZE) ? h[t] : 0;
    if (t < BSIZE) sc[t] = v;
    __syncthreads();
    for (int o = 1; o < BSIZE; o <<= 1) {
        int add = (t < BSIZE && t >= o) ? sc[t - o] : 0;
        __syncthreads();
        if (t < BSIZE) sc[t] += add;
        __syncthreads();
    }
    if (t < BSIZE) {
        int ex = s + sc[t] - v;           // absolute exclusive offset
        curL[t] = ex;
        int node = b * BSIZE + t;
        if (node < N_NODES) {
            offsets[node] = ex;
            cnt[node]     = v;
            dis[node]     = rsqrtf(1.0f + (float)v);
        }
    }
    __syncthreads();
    for (int i = s + t; i < e; i += 256) {
        int p = binned[i];
        int pos = atomicAdd(&curL[p >> 17], 1);
        csr[pos] = p & 0x1FFFF;
    }
}

// ---------------- layer-1 GEMM: h1s = (x @ W1) * dis ----------------
// 4 lanes per row, 2 rows per thread (stride 64), 128 rows / 256-thread WG.
__global__ __launch_bounds__(256) void k_gemm1(
        const float* __restrict__ x, const float* __restrict__ W1,
        const float* __restrict__ dis, float* __restrict__ h1s) {
    __shared__ float sW[F_IN * 20];   // stride 20: 16B-aligned, 2-way bank alias (free)
    for (int idx = threadIdx.x; idx < F_IN * HIDDEN; idx += 256) {
        int k = idx >> 4, j = idx & 15;
        sW[k * 20 + j] = W1[idx];
    }
    __syncthreads();

    int t = threadIdx.x;
    int q = t & 3;
    int row0 = blockIdx.x * 128 + (t >> 2);
    int row1 = row0 + 64;
    bool ok0 = row0 < N_NODES, ok1 = row1 < N_NODES;
    const float* x0 = x + (size_t)row0 * F_IN;
    const float* x1 = x + (size_t)row1 * F_IN;

    float acc[2][16];
#pragma unroll
    for (int rr = 0; rr < 2; ++rr)
#pragma unroll
        for (int j = 0; j < 16; ++j) acc[rr][j] = 0.0f;

#pragma unroll 2
    for (int i = 0; i < 32; ++i) {
        int k0 = i * 16 + q * 4;
        float4 xv0 = ok0 ? *(const float4*)(x0 + k0) : float4{0, 0, 0, 0};
        float4 xv1 = ok1 ? *(const float4*)(x1 + k0) : float4{0, 0, 0, 0};
#pragma unroll
        for (int kk = 0; kk < 4; ++kk) {
            const float* wr = &sW[(k0 + kk) * 20];
            float4 w0 = *(const float4*)(wr);
            float4 w1 = *(const float4*)(wr + 4);
            float4 w2 = *(const float4*)(wr + 8);
            float4 w3 = *(const float4*)(wr + 12);
            float xs0 = (&xv0.x)[kk], xs1 = (&xv1.x)[kk];
            acc[0][0]  = fmaf(xs0, w0.x, acc[0][0]);   acc[1][0]  = fmaf(xs1, w0.x, acc[1][0]);
            acc[0][1]  = fmaf(xs0, w0.y, acc[0][1]);   acc[1][1]  = fmaf(xs1, w0.y, acc[1][1]);
            acc[0][2]  = fmaf(xs0, w0.z, acc[0][2]);   acc[1][2]  = fmaf(xs1, w0.z, acc[1][2]);
            acc[0][3]  = fmaf(xs0, w0.w, acc[0][3]);   acc[1][3]  = fmaf(xs1, w0.w, acc[1][3]);
            acc[0][4]  = fmaf(xs0, w1.x, acc[0][4]);   acc[1][4]  = fmaf(xs1, w1.x, acc[1][4]);
            acc[0][5]  = fmaf(xs0, w1.y, acc[0][5]);   acc[1][5]  = fmaf(xs1, w1.y, acc[1][5]);
            acc[0][6]  = fmaf(xs0, w1.z, acc[0][6]);   acc[1][6]  = fmaf(xs1, w1.z, acc[1][6]);
            acc[0][7]  = fmaf(xs0, w1.w, acc[0][7]);   acc[1][7]  = fmaf(xs1, w1.w, acc[1][7]);
            acc[0][8]  = fmaf(xs0, w2.x, acc[0][8]);   acc[1][8]  = fmaf(xs1, w2.x, acc[1][8]);
            acc[0][9]  = fmaf(xs0, w2.y, acc[0][9]);   acc[1][9]  = fmaf(xs1, w2.y, acc[1][9]);
            acc[0][10] = fmaf(xs0, w2.z, acc[0][10]);  acc[1][10] = fmaf(xs1, w2.z, acc[1][10]);
            acc[0][11] = fmaf(xs0, w2.w, acc[0][11]);  acc[1][11] = fmaf(xs1, w2.w, acc[1][11]);
            acc[0][12] = fmaf(xs0, w3.x, acc[0][12]);  acc[1][12] = fmaf(xs1, w3.x, acc[1][12]);
            acc[0][13] = fmaf(xs0, w3.y, acc[0][13]);  acc[1][13] = fmaf(xs1, w3.y, acc[1][13]);
            acc[0][14] = fmaf(xs0, w3.z, acc[0][14]);  acc[1][14] = fmaf(xs1, w3.z, acc[1][14]);
            acc[0][15] = fmaf(xs0, w3.w, acc[0][15]);  acc[1][15] = fmaf(xs1, w3.w, acc[1][15]);
        }
    }

    // reduce-scatter over the 4 lanes: lane q ends holding j in [4q, 4q+4)
#pragma unroll
    for (int rr = 0; rr < 2; ++rr) {
        float t16[16];
#pragma unroll
        for (int j = 0; j < 16; ++j)
            t16[j] = acc[rr][j] + __shfl_xor(acc[rr][j], 2);
        float k8[8];
#pragma unroll
        for (int j = 0; j < 8; ++j)
            k8[j] = (q & 2) ? t16[8 + j] : t16[j];
        float t8[8];
#pragma unroll
        for (int j = 0; j < 8; ++j)
            t8[j] = k8[j] + __shfl_xor(k8[j], 1);
#pragma unroll
        for (int j = 0; j < 4; ++j)
            acc[rr][j] = (q & 1) ? t8[4 + j] : t8[j];
    }

    if (ok0) {
        float d = dis[row0];
        *(float4*)(h1s + (size_t)row0 * HIDDEN + q * 4) =
            { acc[0][0] * d, acc[0][1] * d, acc[0][2] * d, acc[0][3] * d };
    }
    if (ok1) {
        float d = dis[row1];
        *(float4*)(h1s + (size_t)row1 * HIDDEN + q * 4) =
            { acc[1][0] * d, acc[1][1] * d, acc[1][2] * d, acc[1][3] * d };
    }
}

// ---- agg layer 1: g = relu(dis*(self+Σ h1s[r]) + b1) * dis ----
// 4 lanes per node; coalesced csr reads + shfl broadcast; 4 gathers in flight.
__global__ __launch_bounds__(256) void k_agg1(
        const int* __restrict__ offsets, const int* __restrict__ cnt,
        const int* __restrict__ csr, const float* __restrict__ dis,
        const float* __restrict__ b1,
        const float* __restrict__ h1s, float* __restrict__ g) {
    int t = blockIdx.x * 256 + threadIdx.x;
    int node = t >> 2;
    if (node >= N_NODES) return;          // quad-uniform exit: shfl sources stay active
    int q = t & 3;
    int lanebase = (threadIdx.x & 63) & ~3;

    float4 acc = *(const float4*)(h1s + (size_t)node * HIDDEN + q * 4);  // self
    int start = offsets[node];
    int n = cnt[node];
    int i = 0;
    for (; i + 4 <= n; i += 4) {
        int rv = csr[start + i + q];      // coalesced across the quad
#pragma unroll
        for (int j = 0; j < 4; ++j) {
            int r = __shfl(rv, lanebase + j);
            float4 v = *(const float4*)(h1s + (size_t)r * HIDDEN + q * 4);
            acc.x += v.x; acc.y += v.y; acc.z += v.z; acc.w += v.w;
        }
    }
    for (; i < n; ++i) {
        int r = csr[start + i];           // same addr in quad: broadcast
        float4 v = *(const float4*)(h1s + (size_t)r * HIDDEN + q * 4);
        acc.x += v.x; acc.y += v.y; acc.z += v.z; acc.w += v.w;
    }
    float d = dis[node];
    float4 bq = *(const float4*)(b1 + q * 4);
    float4 r;
    r.x = fmaxf(fmaf(acc.x, d, bq.x), 0.0f) * d;
    r.y = fmaxf(fmaf(acc.y, d, bq.y), 0.0f) * d;
    r.z = fmaxf(fmaf(acc.z, d, bq.z), 0.0f) * d;
    r.w = fmaxf(fmaf(acc.w, d, bq.w), 0.0f) * d;
    *(float4*)(g + (size_t)node * HIDDEN + q * 4) = r;
}

// ---- agg layer 2: out = b2 + (dis*(self+Σ g[r])) @ W2 ----
__global__ __launch_bounds__(256) void k_agg2(
        const int* __restrict__ offsets, const int* __restrict__ cnt,
        const int* __restrict__ csr, const float* __restrict__ dis,
        const float* __restrict__ W2, const float* __restrict__ b2,
        const float* __restrict__ g, float* __restrict__ out) {
    __shared__ float sW[HIDDEN * N_CLS];
    __shared__ float sb2[N_CLS];
    __shared__ float sAgg[64][HIDDEN + 1];
    int t = threadIdx.x;
    for (int i = t; i < HIDDEN * N_CLS; i += 256) sW[i] = W2[i];
    if (t < N_CLS) sb2[t] = b2[t];

    int gt = blockIdx.x * 256 + t;
    int node = gt >> 2;
    int q = t & 3;
    int ln = t >> 2;
    int lanebase = (t & 63) & ~3;

    if (node < N_NODES) {
        float4 acc = *(const float4*)(g + (size_t)node * HIDDEN + q * 4);  // self
        int start = offsets[node];
        int n = cnt[node];
        int i = 0;
        for (; i + 4 <= n; i += 4) {
            int rv = csr[start + i + q];
#pragma unroll
            for (int j = 0; j < 4; ++j) {
                int r = __shfl(rv, lanebase + j);
                float4 v = *(const float4*)(g + (size_t)r * HIDDEN + q * 4);
                acc.x += v.x; acc.y += v.y; acc.z += v.z; acc.w += v.w;
            }
        }
        for (; i < n; ++i) {
            int r = csr[start + i];
            float4 v = *(const float4*)(g + (size_t)r * HIDDEN + q * 4);
            acc.x += v.x; acc.y += v.y; acc.z += v.z; acc.w += v.w;
        }
        float d = dis[node];
        sAgg[ln][q*4+0] = acc.x * d;
        sAgg[ln][q*4+1] = acc.y * d;
        sAgg[ln][q*4+2] = acc.z * d;
        sAgg[ln][q*4+3] = acc.w * d;
    }
    __syncthreads();
    if (node >= N_NODES) return;

    float a[HIDDEN];
#pragma unroll
    for (int j = 0; j < HIDDEN; ++j) a[j] = sAgg[ln][j];

    int c0 = q * 10;
    float o[10];
#pragma unroll
    for (int k = 0; k < 10; ++k) o[k] = sb2[c0 + k];
#pragma unroll
    for (int j = 0; j < HIDDEN; ++j) {
        float aj = a[j];
        const float* wr = &sW[j * N_CLS + c0];
#pragma unroll
        for (int k = 0; k < 10; ++k) o[k] = fmaf(aj, wr[k], o[k]);
    }
    float* op = out + (size_t)node * N_CLS + c0;
#pragma unroll
    for (int k = 0; k < 10; ++k) op[k] = o[k];
}

extern "C" void kernel_launch(void* const* d_in, const int* in_sizes, int n_in,
                              void* d_out, int out_size, void* d_ws, size_t ws_size,
                              hipStream_t stream) {
    const float* x  = (const float*)d_in[0];
    const int*   ei = (const int*)d_in[1];
    const float* W1 = (const float*)d_in[2];
    const float* b1 = (const float*)d_in[3];
    const float* W2 = (const float*)d_in[4];
    const float* b2 = (const float*)d_in[5];
    float* out = (float*)d_out;

    // ws: bucketCnt[784] | boff[784] | cur[784] | offsets[N] | cnt[N] | dis[N] |
    //     binned[E] | csr[E] | h1s[N*16] | g[N*16]   ≈ 27 MB
    char* w = (char*)d_ws;
    int*   bucketCnt = (int*)w;    w += 784 * 4;
    int*   boff      = (int*)w;    w += 784 * 4;
    int*   cur       = (int*)w;    w += 784 * 4;
    int*   offsets   = (int*)w;    w += (size_t)N_NODES * 4;
    int*   cnt       = (int*)w;    w += (size_t)N_NODES * 4;
    float* dis       = (float*)w;  w += (size_t)N_NODES * 4;
    int*   binned    = (int*)w;    w += (size_t)N_EDGES * 4;
    int*   csr       = (int*)w;    w += (size_t)N_EDGES * 4;
    float* h1s       = (float*)w;  w += (size_t)N_NODES * HIDDEN * 4;
    float* g         = (float*)w;

    const int gGemm = (N_NODES + 127) / 128;       // 782
    const int gAgg  = (N_NODES * 4 + 255) / 256;   // 1563

    k_zero <<<(NB + 255) / 256, 256, 0, stream>>>(bucketCnt, NB);
    k_binc <<<NWGBIN, 256, 0, stream>>>(ei, bucketCnt);
    k_bscan<<<1, 1024, 0, stream>>>(bucketCnt, boff, cur);
    k_bfill<<<NWGBIN, 256, 0, stream>>>(ei, cur, binned);
    k_csr  <<<NB, 256, 0, stream>>>(boff, binned, csr, offsets, cnt, dis);
    k_gemm1<<<gGemm, 256, 0, stream>>>(x, W1, dis, h1s);
    k_agg1 <<<gAgg, 256, 0, stream>>>(offsets, cnt, csr, dis, b1, h1s, g);
    k_agg2 <<<gAgg, 256, 0, stream>>>(offsets, cnt, csr, dis, W2, b2, g, out);
}